// Round 3
// baseline (73.689 us; speedup 1.0000x reference)
//
#include <hip/hip_runtime.h>

// CenterLoss, exact masked shortcut:
//   out = mean_i clip(0.5*(||x_i||^2 + ||c_{l_i}||^2) + 0.3 * x_i . c_{l_i}, 1e-12, 1e12)
//         + (C-1)*1e-12          // the B*(C-1) masked-out zeros, each clipped to 1e-12
// B=4096, C=10000, D=512 (fp32 inputs, int32 labels, fp32 scalar output)
//
// Round-2 accounting: dur_us (73.3) = harness ws-poison fill (43.7 us, 256 MiB
// @76% HBM) + input restore (~9 us) + our 2 dispatches (~7 us) + overhead.
// This round: 2 rows per wave (interleaved independent load chains -> 2x MLP),
// 512 blocks, float->double partials per block, 128-thread reduce.

constexpr int BATCH = 4096;
constexpr int NCLASS = 10000;
constexpr int DIM = 512;
constexpr int WAVES_PER_BLOCK = 4;
constexpr int NBLOCKS = BATCH / (2 * WAVES_PER_BLOCK);   // 512 (2 rows/wave)

__global__ __launch_bounds__(256) void center_loss_rows(
    const float* __restrict__ x,
    const float* __restrict__ centers,
    const int* __restrict__ labels,
    double* __restrict__ partial) {
  const int lane = (int)(threadIdx.x & 63);
  const int widx = (int)(threadIdx.x >> 6);
  const int wave_global = (int)(blockIdx.x * WAVES_PER_BLOCK + widx);
  const int row0 = wave_global * 2;
  const int row1 = row0 + 1;

  __shared__ float wave_val[WAVES_PER_BLOCK];

  // Two independent label->center dependency chains per wave.
  const int l0 = labels[row0];
  const int l1 = labels[row1];
  const float* __restrict__ x0 = x + (size_t)row0 * DIM;
  const float* __restrict__ x1 = x + (size_t)row1 * DIM;
  const float* __restrict__ c0 = centers + (size_t)l0 * DIM;
  const float* __restrict__ c1 = centers + (size_t)l1 * DIM;

  const int o0 = lane * 4;
  const int o1 = 256 + lane * 4;

  // Issue all 8 float4 loads up front (compiler schedules them; only the c*
  // loads depend on the label loads). 2 rows x (x,c) x 2 chunks.
  const float4 xa0 = *(const float4*)(x0 + o0);
  const float4 xa1 = *(const float4*)(x0 + o1);
  const float4 xb0 = *(const float4*)(x1 + o0);
  const float4 xb1 = *(const float4*)(x1 + o1);
  const float4 ca0 = *(const float4*)(c0 + o0);
  const float4 ca1 = *(const float4*)(c0 + o1);
  const float4 cb0 = *(const float4*)(c1 + o0);
  const float4 cb1 = *(const float4*)(c1 + o1);

  float xx0 = xa0.x*xa0.x + xa0.y*xa0.y + xa0.z*xa0.z + xa0.w*xa0.w
            + xa1.x*xa1.x + xa1.y*xa1.y + xa1.z*xa1.z + xa1.w*xa1.w;
  float cc0 = ca0.x*ca0.x + ca0.y*ca0.y + ca0.z*ca0.z + ca0.w*ca0.w
            + ca1.x*ca1.x + ca1.y*ca1.y + ca1.z*ca1.z + ca1.w*ca1.w;
  float xc0 = xa0.x*ca0.x + xa0.y*ca0.y + xa0.z*ca0.z + xa0.w*ca0.w
            + xa1.x*ca1.x + xa1.y*ca1.y + xa1.z*ca1.z + xa1.w*ca1.w;

  float xx1 = xb0.x*xb0.x + xb0.y*xb0.y + xb0.z*xb0.z + xb0.w*xb0.w
            + xb1.x*xb1.x + xb1.y*xb1.y + xb1.z*xb1.z + xb1.w*xb1.w;
  float cc1 = cb0.x*cb0.x + cb0.y*cb0.y + cb0.z*cb0.z + cb0.w*cb0.w
            + cb1.x*cb1.x + cb1.y*cb1.y + cb1.z*cb1.z + cb1.w*cb1.w;
  float xc1 = xb0.x*cb0.x + xb0.y*cb0.y + xb0.z*cb0.z + xb0.w*cb0.w
            + xb1.x*cb1.x + xb1.y*cb1.y + xb1.z*cb1.z + xb1.w*cb1.w;

#pragma unroll
  for (int sh = 32; sh > 0; sh >>= 1) {
    xx0 += __shfl_down(xx0, sh, 64);
    cc0 += __shfl_down(cc0, sh, 64);
    xc0 += __shfl_down(xc0, sh, 64);
    xx1 += __shfl_down(xx1, sh, 64);
    cc1 += __shfl_down(cc1, sh, 64);
    xc1 += __shfl_down(xc1, sh, 64);
  }
  // clamp each row AFTER masking, faithful to reference
  float s0 = fminf(fmaxf(0.5f * (xx0 + cc0) + 0.3f * xc0, 1e-12f), 1e12f);
  float s1 = fminf(fmaxf(0.5f * (xx1 + cc1) + 0.3f * xc1, 1e-12f), 1e12f);

  if (lane == 0) wave_val[widx] = s0 + s1;
  __syncthreads();
  if (threadIdx.x == 0) {
    partial[blockIdx.x] = (double)wave_val[0] + (double)wave_val[1] +
                          (double)wave_val[2] + (double)wave_val[3];
  }
}

__global__ __launch_bounds__(128) void center_loss_reduce(
    const double* __restrict__ partial,
    float* __restrict__ out) {
  const int tid  = (int)threadIdx.x;
  const int lane = tid & 63;
  const int widx = tid >> 6;

  __shared__ double wave_sum[2];

  // 512 partials / 128 threads = 4 each
  double s = partial[tid] + partial[tid + 128] +
             partial[tid + 256] + partial[tid + 384];
#pragma unroll
  for (int sh = 32; sh > 0; sh >>= 1) {
    s += __shfl_down(s, sh, 64);
  }
  if (lane == 0) wave_sum[widx] = s;
  __syncthreads();
  if (tid == 0) {
    double total = wave_sum[0] + wave_sum[1];
    total += (double)BATCH * (double)(NCLASS - 1) * 1e-12;  // clipped zeros
    out[0] = (float)(total / (double)BATCH);
  }
}

extern "C" void kernel_launch(void* const* d_in, const int* in_sizes, int n_in,
                              void* d_out, int out_size, void* d_ws, size_t ws_size,
                              hipStream_t stream) {
  const float* x       = (const float*)d_in[0];
  const float* centers = (const float*)d_in[1];
  const int*   labels  = (const int*)d_in[2];
  float*       out     = (float*)d_out;
  double*      partial = (double*)d_ws;   // 512 doubles = 4 KB of ws

  center_loss_rows<<<NBLOCKS, 256, 0, stream>>>(x, centers, labels, partial);
  center_loss_reduce<<<1, 128, 0, stream>>>(partial, out);
}